// Round 2
// baseline (567.909 us; speedup 1.0000x reference)
//
#include <hip/hip_runtime.h>

// Inputs and output are FP32 (per the reference). Internal GEMM/attention
// compute is bf16 MFMA with fp32 accumulate; bf16 stored as unsigned short.

typedef __attribute__((ext_vector_type(8))) short short8;    // 8 bf16 = 1 MFMA A/B frag
typedef __attribute__((ext_vector_type(4))) short short4v;   // 4 bf16 = 8B vector
typedef __attribute__((ext_vector_type(4))) float floatx4;   // MFMA C/D frag
typedef __attribute__((ext_vector_type(4))) int int4v;

__device__ __forceinline__ float bf2f(unsigned short u) {
    return __uint_as_float(((unsigned int)u) << 16);
}
__device__ __forceinline__ unsigned short f2bf(float f) {
    unsigned int u = __float_as_uint(f);
    u += 0x7FFFu + ((u >> 16) & 1u);   // RNE
    return (unsigned short)(u >> 16);
}
__device__ __forceinline__ int pack2bf(float a, float b) {
    return (int)f2bf(a) | ((int)f2bf(b) << 16);
}
// Single-instruction packed f32->bf16 pair (RNE, matches f2bf).
__device__ __forceinline__ unsigned int cvt_pk_bf16(float lo, float hi) {
    unsigned int r;
    asm("v_cvt_pk_bf16_f32 %0, %1, %2" : "=v"(r) : "v"(lo), "v"(hi));
    return r;
}

// Q pre-scale folds softmax's 1/sqrt(64) AND log2(e) so the attention kernel
// can use the raw v_exp_f32 (2^x) instead of mul+exp: 0.125 * 1.4426950408889634
#define Q_PRESCALE 0.18033688011112043f

#if __has_builtin(__builtin_amdgcn_exp2f)
__device__ __forceinline__ float fast_exp2(float x) { return __builtin_amdgcn_exp2f(x); }
#else
__device__ __forceinline__ float fast_exp2(float x) { return __expf(x * 0.6931471805599453f); }
#endif

#if __has_builtin(__builtin_amdgcn_permlane32_swap) && __has_builtin(__builtin_amdgcn_permlane16_swap)
#define HAVE_PERMLANE 1
#else
#define HAVE_PERMLANE 0
#endif

// Async global->LDS, 16 B per lane. LDS dest = wave-uniform base + lane*16.
__device__ __forceinline__ void async16(const unsigned short* g, unsigned short* l) {
    __builtin_amdgcn_global_load_lds(
        (const __attribute__((address_space(1))) unsigned int*)g,
        (__attribute__((address_space(3))) unsigned int*)l, 16, 0, 0);
}

// ---------------------------------------------------------------------------
// FP32 -> BF16 elementwise convert. grid = n/1024, block 256.
// ---------------------------------------------------------------------------
__global__ __launch_bounds__(256)
void cvt_f2b(const float* __restrict__ in, unsigned short* __restrict__ out) {
    const int i = (blockIdx.x * 256 + threadIdx.x) * 4;
    float4 v = *(const float4*)&in[i];
    short4v o;
    o[0] = (short)f2bf(v.x); o[1] = (short)f2bf(v.y);
    o[2] = (short)f2bf(v.z); o[3] = (short)f2bf(v.w);
    *(short4v*)&out[i] = o;
}

// ---------------------------------------------------------------------------
// 256x256-tile 8-phase GEMM (T2+T3+T4+T5 template, plain HIP).
// C[M,N] = A[M,K] @ W[N,K]^T (+bias fp32) (+PReLU) (+Q_PRESCALE on cols<qcols)
// bf16 in/out, fp32 acc. BK=64, 8 waves (2M x 4N), 512 threads, 128 KiB LDS
// double-buffer. Per K-tile: 4 phases, quadrant order (0,0),(0,1),(1,1),(1,0)
// -> ds_reads per phase 12/4/8/0. Half-tile stream (A0,B0,B1,A1 per tile)
// staged 7 half-tiles ahead; ONE counted vmcnt(6) per K-tile at the boundary
// (3 half-tiles always in flight across barriers; never drained to 0 in the
// main loop). st_16x32 XOR swizzle (col ^= 16 elems when row&4) applied via
// inverse-swizzled GLOBAL source + swizzled ds_read col (both lane-constant).
// WAR ledger (stage into region vs last read of region, 2 tiles apart):
//   A0 staged p1(t), read p0(t)   | B0 staged p2(t), read p0(t)
//   B1 staged p3(t), read p1(t)   | A1 staged p0(t+1), read p2(t)
// each read drains (lgkmcnt) >=1 barrier before its re-stage is issued.
// ---------------------------------------------------------------------------
__global__ __launch_bounds__(512, 2)
void gemm256(const unsigned short* __restrict__ A,
             const unsigned short* __restrict__ W,
             const float* __restrict__ bias,   // nullable, len N, fp32
             const float* __restrict__ prelu,  // nullable, scalar, fp32
             unsigned short* __restrict__ C,
             int N, int K, int qcols, int NNT) {
    __shared__ alignas(16) unsigned short lA[2][256 * 64];
    __shared__ alignas(16) unsigned short lB[2][256 * 64];

    // Bijective XCD swizzle (m204), then wgid = mt*NNT + nt.
    const int nwg = gridDim.x;
    const int orig = blockIdx.x;
    const int q8 = nwg >> 3, r8 = nwg & 7, xx = orig & 7, rest = orig >> 3;
    const int wgid = (xx < r8 ? xx * (q8 + 1) : r8 * (q8 + 1) + (xx - r8) * q8) + rest;
    const int mt = wgid / NNT, nt = wgid % NNT;
    const int m0 = mt * 256, n0 = nt * 256;

    const int tid  = threadIdx.x;
    const int lane = tid & 63;
    const int wave = tid >> 6;            // 0..7
    const int lr = lane & 15, lq = lane >> 4;
    const int wrow = (wave >> 2) * 64;    // wave row chunk within each M-half
    const int wcol = (wave & 3) * 32;     // wave col chunk within each N-half
    const int srow = lane >> 3;           // staging row within 8-row chunk
    const int scol = ((lane & 7) * 8) ^ ((lane & 32) ? 16 : 0);  // inv-swz src col
    const int kxo  = (lq * 8) ^ ((lr & 4) ? 16 : 0);             // swz read col

    const int NT = K >> 6;

    floatx4 acc[2][2][4][2] = {};   // [mh][nh][i][j]

    auto stA = [&](int d, int tt, int h) {
        #pragma unroll
        for (int it = 0; it < 2; ++it) {
            const int rb = h * 128 + (wave * 2 + it) * 8;
            async16(&A[(size_t)(m0 + rb + srow) * K + tt * 64 + scol], &lA[d][rb * 64]);
        }
    };
    auto stB = [&](int d, int tt, int h) {
        #pragma unroll
        for (int it = 0; it < 2; ++it) {
            const int rb = h * 128 + (wave * 2 + it) * 8;
            async16(&W[(size_t)(n0 + rb + srow) * K + tt * 64 + scol], &lB[d][rb * 64]);
        }
    };

    // Prologue: stage stream A0,B0,B1,A1 (tile0) ; A0,B0,B1 (tile1) = 14 loads;
    // wait all of tile0 (leave tile1's 6 in flight).
    stA(0, 0, 0); stB(0, 0, 0); stB(0, 0, 1); stA(0, 0, 1);
    stA(1, 1, 0); stB(1, 1, 0); stB(1, 1, 1);
    asm volatile("s_waitcnt vmcnt(6)" ::: "memory");
    __builtin_amdgcn_s_barrier();
    asm volatile("" ::: "memory");

    short8 af[4][2], b0[2][2], b1[2][2];

    for (int t = 0; t < NT; ++t) {
        const int d = t & 1, e = d ^ 1;

        // ---- phase 0: read A(mh=0) + B0; stage A1(t+1); MFMA quad (0,0)
        #pragma unroll
        for (int i = 0; i < 4; ++i)
            #pragma unroll
            for (int s = 0; s < 2; ++s)
                af[i][s] = *(const short8*)&lA[d][(wrow + i * 16 + lr) * 64 + s * 32 + kxo];
        #pragma unroll
        for (int j = 0; j < 2; ++j)
            #pragma unroll
            for (int s = 0; s < 2; ++s)
                b0[j][s] = *(const short8*)&lB[d][(wcol + j * 16 + lr) * 64 + s * 32 + kxo];
        if (t + 1 < NT) stA(e, t + 1, 1);
        __builtin_amdgcn_s_barrier();
        asm volatile("s_waitcnt lgkmcnt(0)" ::: "memory");
        __builtin_amdgcn_s_setprio(1);
        #pragma unroll
        for (int s = 0; s < 2; ++s)
            #pragma unroll
            for (int i = 0; i < 4; ++i)
                #pragma unroll
                for (int j = 0; j < 2; ++j)
                    acc[0][0][i][j] = __builtin_amdgcn_mfma_f32_16x16x32_bf16(
                        af[i][s], b0[j][s], acc[0][0][i][j], 0, 0, 0);
        __builtin_amdgcn_s_setprio(0);
        __builtin_amdgcn_s_barrier();
        asm volatile("" ::: "memory");

        // ---- phase 1: read B1; stage A0(t+2); MFMA quad (0,1)
        #pragma unroll
        for (int j = 0; j < 2; ++j)
            #pragma unroll
            for (int s = 0; s < 2; ++s)
                b1[j][s] = *(const short8*)&lB[d][(128 + wcol + j * 16 + lr) * 64 + s * 32 + kxo];
        if (t + 2 < NT) stA(d, t + 2, 0);
        __builtin_amdgcn_s_barrier();
        asm volatile("s_waitcnt lgkmcnt(0)" ::: "memory");
        __builtin_amdgcn_s_setprio(1);
        #pragma unroll
        for (int s = 0; s < 2; ++s)
            #pragma unroll
            for (int i = 0; i < 4; ++i)
                #pragma unroll
                for (int j = 0; j < 2; ++j)
                    acc[0][1][i][j] = __builtin_amdgcn_mfma_f32_16x16x32_bf16(
                        af[i][s], b1[j][s], acc[0][1][i][j], 0, 0, 0);
        __builtin_amdgcn_s_setprio(0);
        __builtin_amdgcn_s_barrier();
        asm volatile("" ::: "memory");

        // ---- phase 2: read A(mh=1); stage B0(t+2); MFMA quad (1,1)
        #pragma unroll
        for (int i = 0; i < 4; ++i)
            #pragma unroll
            for (int s = 0; s < 2; ++s)
                af[i][s] = *(const short8*)&lA[d][(128 + wrow + i * 16 + lr) * 64 + s * 32 + kxo];
        if (t + 2 < NT) stB(d, t + 2, 0);
        __builtin_amdgcn_s_barrier();
        asm volatile("s_waitcnt lgkmcnt(0)" ::: "memory");
        __builtin_amdgcn_s_setprio(1);
        #pragma unroll
        for (int s = 0; s < 2; ++s)
            #pragma unroll
            for (int i = 0; i < 4; ++i)
                #pragma unroll
                for (int j = 0; j < 2; ++j)
                    acc[1][1][i][j] = __builtin_amdgcn_mfma_f32_16x16x32_bf16(
                        af[i][s], b1[j][s], acc[1][1][i][j], 0, 0, 0);
        __builtin_amdgcn_s_setprio(0);
        __builtin_amdgcn_s_barrier();
        asm volatile("" ::: "memory");

        // ---- phase 3: no reads; stage B1(t+2); MFMA quad (1,0); boundary vmcnt
        if (t + 2 < NT) stB(d, t + 2, 1);
        __builtin_amdgcn_s_barrier();
        asm volatile("" ::: "memory");
        __builtin_amdgcn_s_setprio(1);
        #pragma unroll
        for (int s = 0; s < 2; ++s)
            #pragma unroll
            for (int i = 0; i < 4; ++i)
                #pragma unroll
                for (int j = 0; j < 2; ++j)
                    acc[1][0][i][j] = __builtin_amdgcn_mfma_f32_16x16x32_bf16(
                        af[i][s], b0[j][s], acc[1][0][i][j], 0, 0, 0);
        __builtin_amdgcn_s_setprio(0);
        // Boundary: all 4 half-tiles of t+1 done; keep t+2's 3 halves in flight.
        if (t + 2 < NT) {
            asm volatile("s_waitcnt vmcnt(6)" ::: "memory");
        } else {
            asm volatile("s_waitcnt vmcnt(0)" ::: "memory");
        }
        __builtin_amdgcn_s_barrier();
        asm volatile("" ::: "memory");
    }

    // Epilogue: bias / PReLU / Q prescale, bf16 store.
    const bool hasb = (bias != nullptr);
    const bool hasp = (prelu != nullptr);
    const float slope = hasp ? prelu[0] : 0.f;
    #pragma unroll
    for (int mh = 0; mh < 2; ++mh)
        #pragma unroll
        for (int nh = 0; nh < 2; ++nh)
            #pragma unroll
            for (int j = 0; j < 2; ++j) {
                const int gc = n0 + nh * 128 + wcol + j * 16 + lr;
                const float bv = hasb ? bias[gc] : 0.f;
                const float cs = (gc < qcols) ? Q_PRESCALE : 1.f;
                #pragma unroll
                for (int i = 0; i < 4; ++i) {
                    const int gr = m0 + mh * 128 + wrow + i * 16 + lq * 4;
                    #pragma unroll
                    for (int r = 0; r < 4; ++r) {
                        float v = acc[mh][nh][i][j][r] + bv;
                        if (hasp && v < 0.f) v *= slope;
                        C[(size_t)(gr + r) * N + gc] = f2bf(v * cs);
                    }
                }
            }
}

// ---------------------------------------------------------------------------
// V transpose: vt[(bh*64 + d)*2048 + key] = qkv[(b*2048+key)*3072 + 2048 + h*64 + d]
// ---------------------------------------------------------------------------
__global__ __launch_bounds__(256)
void transpose_v(const unsigned short* __restrict__ qkv,
                 unsigned short* __restrict__ vt) {
    const int kt = blockIdx.x;   // key tile 0..31
    const int bh = blockIdx.y;   // 0..63
    const int b = bh >> 4, h = bh & 15;
    __shared__ unsigned short tile[64 * 65];
    for (int t = threadIdx.x; t < 512; t += 256) {
        const int key = t >> 3, c8 = (t & 7) << 3;
        short8 v8 = *(const short8*)&qkv[((size_t)(b * 2048 + kt * 64 + key)) * 3072 +
                                         2048 + h * 64 + c8];
        #pragma unroll
        for (int e = 0; e < 8; ++e)
            tile[key * 65 + c8 + e] = (unsigned short)v8[e];
    }
    __syncthreads();
    for (int t = threadIdx.x; t < 512; t += 256) {
        const int d = t >> 3, k8 = (t & 7) << 3;
        short8 o;
        #pragma unroll
        for (int e = 0; e < 8; ++e)
            o[e] = (short)tile[(k8 + e) * 65 + d];
        *(short8*)&vt[((size_t)bh * 64 + d) * 2048 + kt * 64 + k8] = o;
    }
}

// ---------------------------------------------------------------------------
// Flash attention, S^T formulation, NO-MAX softmax (exp2; log2e folded into
// the Q pre-scale). FOUR WAVES PER BLOCK sharing the staged K/V chunk;
// double-buffered, raw s_barrier + counted `s_waitcnt vmcnt(4)`.
// K/V LDS tiles XOR-swizzled; P redistribution via permlane32/16_swap.
// Grid 512: id = qg*64 + bh -> id%8 = bh%8 (XCD locality for K/V).
// ---------------------------------------------------------------------------
__global__ __launch_bounds__(256, 2)
void attn_kernel(const unsigned short* __restrict__ qkv,
                 const unsigned short* __restrict__ vt,
                 unsigned short* __restrict__ o_attn) {
    const int id = blockIdx.x;
    const int qg = id >> 6;     // 0..7
    const int bh = id & 63;     // 0..63
    const int b = bh >> 4, h = bh & 15;
    const int tid  = threadIdx.x;
    const int lane = tid & 63;
    const int wave = tid >> 6;  // 0..3
    const int lr = lane & 15;
    const int lq = lane >> 4;
    const int q0 = (qg * 4 + wave) * 64;
    const size_t row0 = (size_t)(b * 2048) * 3072;

    __shared__ alignas(16) unsigned short lK[2][64 * 64];   // [key][d] (swizzled)
    __shared__ alignas(16) unsigned short lV[2][64 * 64];   // [d][key] (swizzled)

    // Q fragments (B-operand): [n = q = j*16+lr][k = s*32 + lq*8 + jj]
    short8 qf[4][2];
    #pragma unroll
    for (int j = 0; j < 4; ++j)
        #pragma unroll
        for (int s = 0; s < 2; ++s)
            qf[j][s] = *(const short8*)&qkv[row0 + (size_t)(q0 + j * 16 + lr) * 3072 +
                                            h * 64 + s * 32 + lq * 8];

    floatx4 oacc[4][4] = {};   // [dtile i][qtile j]: d=i*16+lq*4+r, q=j*16+lr
    float l_i[4] = {0.f, 0.f, 0.f, 0.f};

    const int srow = lane >> 3;                        // staging row-within-8
    const int scol = (((lane & 7) ^ srow)) << 3;       // swizzled source chunk
    const int kx = lr & 7;                             // read-side swizzle key

    // Stage one 64-key chunk into buffer bi: this wave's 2 K rows-of-8 + 2 V.
    auto stage = [&](int bi, int kc) {
        #pragma unroll
        for (int it2 = 0; it2 < 2; ++it2) {
            const int it = wave * 2 + it2;
            const int row = it * 8 + srow;            // row&7 == srow
            async16(&qkv[row0 + (size_t)(kc + row) * 3072 + 1024 + h * 64 + scol],
                    &lK[bi][it * 512 + lane * 8]);
            async16(&vt[((size_t)bh * 64 + row) * 2048 + kc + scol],
                    &lV[bi][it * 512 + lane * 8]);
        }
    };

    // Drain Q loads so vmcnt arithmetic below counts only staging loads.
    asm volatile("s_waitcnt vmcnt(0)" ::: "memory");
    stage(0, 0);

    #pragma unroll 1
    for (int c = 0; c < 32; ++c) {
        const int cur = c & 1;
        if (c + 1 < 32) {
            stage(cur ^ 1, (c + 1) * 64);            // issue next chunk's 4 loads
            asm volatile("s_waitcnt vmcnt(4)" ::: "memory");
        } else {
            asm volatile("s_waitcnt vmcnt(0)" ::: "memory");
        }
        __builtin_amdgcn_s_barrier();                // all waves staged `cur`
        asm volatile("" ::: "memory");

        // S^T = K·Q^T
        floatx4 sacc[4][4] = {};   // [keytile i][qtile j]: key=i*16+lq*4+r
        #pragma unroll
        for (int s = 0; s < 2; ++s) {
            short8 kf[4];
            #pragma unroll
            for (int i = 0; i < 4; ++i) {
                const int r = i * 16 + lr;
                kf[i] = *(const short8*)&lK[cur][r * 64 + (((s * 4 + lq) ^ kx) << 3)];
            }
            #pragma unroll
            for (int i = 0; i < 4; ++i)
                #pragma unroll
                for (int j = 0; j < 4; ++j)
                    sacc[i][j] = __builtin_amdgcn_mfma_f32_16x16x32_bf16(
                        kf[i], qf[j][s], sacc[i][j], 0, 0, 0);
        }

        // P = 2^S (log2e pre-folded), packed bf16 pairs via v_cvt_pk_bf16_f32.
        unsigned int pkd[4][4][2];
        #pragma unroll
        for (int i = 0; i < 4; ++i)
            #pragma unroll
            for (int j = 0; j < 4; ++j) {
                const float e0 = fast_exp2(sacc[i][j][0]);
                const float e1 = fast_exp2(sacc[i][j][1]);
                const float e2 = fast_exp2(sacc[i][j][2]);
                const float e3 = fast_exp2(sacc[i][j][3]);
                l_i[j] += (e0 + e1) + (e2 + e3);
                pkd[i][j][0] = cvt_pk_bf16(e0, e1);
                pkd[i][j][1] = cvt_pk_bf16(e2, e3);
            }

        // O^T += V^T·P^T.
        #pragma unroll
        for (int s = 0; s < 2; ++s) {
            short8 vf[4];
            #pragma unroll
            for (int i = 0; i < 4; ++i) {
                const int r = i * 16 + lr;
                vf[i] = *(const short8*)&lV[cur][r * 64 + (((s * 4 + lq) ^ kx) << 3)];
            }
            short8 bq[4];
            #pragma unroll
            for (int j = 0; j < 4; ++j) {
                int4v iv;
#if HAVE_PERMLANE
                auto p0 = __builtin_amdgcn_permlane32_swap(
                    pkd[2 * s][j][0], pkd[2 * s + 1][j][0], false, false);
                auto w0 = __builtin_amdgcn_permlane16_swap(p0[0], p0[1], false, false);
                auto p1 = __builtin_amdgcn_permlane32_swap(
                    pkd[2 * s][j][1], pkd[2 * s + 1][j][1], false, false);
                auto w1 = __builtin_amdgcn_permlane16_swap(p1[0], p1[1], false, false);
                iv[0] = (int)w0[0]; iv[1] = (int)w1[0];
                iv[2] = (int)w0[1]; iv[3] = (int)w1[1];
#else
                const int src0 = lr + ((lq & 1) * 2) * 16;
                const int src1 = src0 + 16;
                const bool hi = (lq >> 1) != 0;
                int a0 = __shfl((int)pkd[2 * s][j][0], src0, 64);
                int c0 = __shfl((int)pkd[2 * s + 1][j][0], src0, 64);
                int a1 = __shfl((int)pkd[2 * s][j][1], src0, 64);
                int c1 = __shfl((int)pkd[2 * s + 1][j][1], src0, 64);
                int a2 = __shfl((int)pkd[2 * s][j][0], src1, 64);
                int c2 = __shfl((int)pkd[2 * s + 1][j][0], src1, 64);
                int a3 = __shfl((int)pkd[2 * s][j][1], src1, 64);
                int c3 = __shfl((int)pkd[2 * s + 1][j][1], src1, 64);
                iv[0] = hi ? c0 : a0;
                iv[1] = hi ? c1 : a1;
                iv[2] = hi ? c2 : a2;
                iv[3] = hi ? c3 : a3;
#endif
                bq[j] = __builtin_bit_cast(short8, iv);
            }
            #pragma unroll
            for (int j = 0; j < 4; ++j)
                #pragma unroll
                for (int i = 0; i < 4; ++i)
                    oacc[i][j] = __builtin_amdgcn_mfma_f32_16x16x32_bf16(
                        vf[i], bq[j], oacc[i][j], 0, 0, 0);
        }

        asm volatile("s_waitcnt lgkmcnt(0)" ::: "memory");
        __builtin_amdgcn_s_barrier();
        asm volatile("" ::: "memory");
    }

    // Epilogue: reduce l across the 4 lq groups, normalize, packed stores.
    #pragma unroll
    for (int j = 0; j < 4; ++j) {
        l_i[j] += __shfl_xor(l_i[j], 16, 64);
        l_i[j] += __shfl_xor(l_i[j], 32, 64);
        const float rl = 1.f / l_i[j];
        const int q = q0 + j * 16 + lr;
        #pragma unroll
        for (int i = 0; i < 4; ++i) {
            int2 pk;
            pk.x = pack2bf(oacc[i][j][0] * rl, oacc[i][j][1] * rl);
            pk.y = pack2bf(oacc[i][j][2] * rl, oacc[i][j][3] * rl);
            *(int2*)&o_attn[((size_t)(b * 2048 + q)) * 1024 + h * 64 + i * 16 + lq * 4] = pk;
        }
    }
}

// ---------------------------------------------------------------------------
// LN1: out_bf16 = LayerNorm(x_fp32 + res_bf16) * g + b   (g,b fp32)
// ---------------------------------------------------------------------------
__global__ __launch_bounds__(256)
void ln_f32_bf16(const float* __restrict__ x,
                 const unsigned short* __restrict__ res,
                 const float* __restrict__ g,
                 const float* __restrict__ bta,
                 unsigned short* __restrict__ out) {
    const int row = blockIdx.x;
    const int t = threadIdx.x;
    const size_t base = (size_t)row * 1024;

    float4 xv = *(const float4*)&x[base + t * 4];
    short4v rv = *(const short4v*)&res[base + t * 4];
    float v[4] = { xv.x + bf2f((unsigned short)rv[0]),
                   xv.y + bf2f((unsigned short)rv[1]),
                   xv.z + bf2f((unsigned short)rv[2]),
                   xv.w + bf2f((unsigned short)rv[3]) };
    float s = 0.f, s2 = 0.f;
    #pragma unroll
    for (int k = 0; k < 4; ++k) { s += v[k]; s2 += v[k] * v[k]; }
    #pragma unroll
    for (int off = 32; off > 0; off >>= 1) {
        s  += __shfl_xor(s, off, 64);
        s2 += __shfl_xor(s2, off, 64);
    }
    __shared__ float red[8];
    const int wave = t >> 6;
    if ((t & 63) == 0) { red[wave] = s; red[4 + wave] = s2; }
    __syncthreads();
    s  = red[0] + red[1] + red[2] + red[3];
    s2 = red[4] + red[5] + red[6] + red[7];
    const float mean = s * (1.f / 1024.f);
    const float var  = fmaxf(s2 * (1.f / 1024.f) - mean * mean, 0.f);
    const float inv  = rsqrtf(var + 1e-5f);

    short4v ov;
    #pragma unroll
    for (int k = 0; k < 4; ++k) {
        int c = t * 4 + k;
        ov[k] = (short)f2bf((v[k] - mean) * inv * g[c] + bta[c]);
    }
    *(short4v*)&out[base + t * 4] = ov;
}

// ---------------------------------------------------------------------------
// LN2: out_fp32 = LayerNorm(x_bf16 + res_bf16) * g + b
// ---------------------------------------------------------------------------
__global__ __launch_bounds__(256)
void ln_bf16_f32(const unsigned short* __restrict__ x,
                 const unsigned short* __restrict__ res,
                 const float* __restrict__ g,
                 const float* __restrict__ bta,
                 float* __restrict__ out) {
    const int row = blockIdx.x;
    const int t = threadIdx.x;
    const size_t base = (size_t)row * 1024;

    short4v xv = *(const short4v*)&x[base + t * 4];
    short4v rv = *(const short4v*)&res[base + t * 4];
    float v[4];
    float s = 0.f, s2 = 0.f;
    #pragma unroll
    for (int k = 0; k < 4; ++k) {
        v[k] = bf2f((unsigned short)xv[k]) + bf2f((unsigned short)rv[k]);
        s += v[k];
        s2 += v[k] * v[k];
    }
    #pragma unroll
    for (int off = 32; off > 0; off >>= 1) {
        s  += __shfl_xor(s, off, 64);
        s2 += __shfl_xor(s2, off, 64);
    }
    __shared__ float red[8];
    const int wave = t >> 6;
    if ((t & 63) == 0) { red[wave] = s; red[4 + wave] = s2; }
    __syncthreads();
    s  = red[0] + red[1] + red[2] + red[3];
    s2 = red[4] + red[5] + red[6] + red[7];
    const float mean = s * (1.f / 1024.f);
    const float var  = fmaxf(s2 * (1.f / 1024.f) - mean * mean, 0.f);
    const float inv  = rsqrtf(var + 1e-5f);

    float4 ov;
    ov.x = (v[0] - mean) * inv * g[t * 4 + 0] + bta[t * 4 + 0];
    ov.y = (v[1] - mean) * inv * g[t * 4 + 1] + bta[t * 4 + 1];
    ov.z = (v[2] - mean) * inv * g[t * 4 + 2] + bta[t * 4 + 2];
    ov.w = (v[3] - mean) * inv * g[t * 4 + 3] + bta[t * 4 + 3];
    *(float4*)&out[base + t * 4] = ov;
}

// ---------------------------------------------------------------------------
extern "C" void kernel_launch(void* const* d_in, const int* in_sizes, int n_in,
                              void* d_out, int out_size, void* d_ws, size_t ws_size,
                              hipStream_t stream) {
    const float* x      = (const float*)d_in[0];
    const float* qkv_w  = (const float*)d_in[1];
    const float* proj_w = (const float*)d_in[2];
    const float* proj_b = (const float*)d_in[3];
    const float* ln1_g  = (const float*)d_in[4];
    const float* ln1_b  = (const float*)d_in[5];
    const float* w1     = (const float*)d_in[6];
    const float* b1     = (const float*)d_in[7];
    const float* prelu  = (const float*)d_in[8];
    const float* w2     = (const float*)d_in[9];
    const float* b2     = (const float*)d_in[10];
    const float* ln2_g  = (const float*)d_in[11];
    const float* ln2_b  = (const float*)d_in[12];
    float* out = (float*)d_out;

    // Workspace (bf16 buffers), peak 120 MB (validated):
    //  [0,24)   weights (qkv 6 | proj 2 | w1 8 | w2 8)
    //  [24,40)  xb -> vt (after qkv GEMM) -> pout (after attn) -> h2
    //  [40,88)  qkvb -> x1b[40,56)       [88,104) oat       h1 = [56,120)
    char* ws = (char*)d_ws;
    const size_t MB = 1024 * 1024;
    unsigned short* wqkvb  = (unsigned short*)(ws);
    unsigned short* wprojb = (unsigned short*)(ws + 6 * MB);
    unsigned short* w1b    = (unsigned short*)(ws + 8 * MB);
    unsigned short* w2b    = (unsigned short*)(ws + 16 * MB);
    unsigned short* xb     = (unsigned short*)(ws + 24 * MB);
    unsigned short* vtb    = (unsigned short*)(ws + 24 * MB);  // alias xb (dead)
    unsigned short* qkvb   = (unsigned short*)(ws + 40 * MB);
    unsigned short* oat    = (unsigned short*)(ws + 88 * MB);
    unsigned short* pout   = (unsigned short*)(ws + 24 * MB);  // alias vt (dead)
    unsigned short* x1b    = (unsigned short*)(ws + 40 * MB);
    unsigned short* h1     = (unsigned short*)(ws + 56 * MB);
    unsigned short* h2     = (unsigned short*)(ws + 24 * MB);

    // 0) fp32 -> bf16 conversions
    cvt_f2b<<<8192, 256, 0, stream>>>(x,      xb);
    cvt_f2b<<<3072, 256, 0, stream>>>(qkv_w,  wqkvb);
    cvt_f2b<<<1024, 256, 0, stream>>>(proj_w, wprojb);
    cvt_f2b<<<4096, 256, 0, stream>>>(w1,     w1b);
    cvt_f2b<<<4096, 256, 0, stream>>>(w2,     w2b);

    // 1) qkv = x @ qkv_w^T  [8192,3072], Q columns (<1024) pre-scaled by
    //    0.125*log2e (softmax via exp2). grid 32x12.
    gemm256<<<dim3(32 * 12), 512, 0, stream>>>(xb, wqkvb, nullptr, nullptr,
                                               qkvb, 3072, 1024, 1024, 12);
    // 1b) V transpose -> vt[bh][d][key]  (xb dead)
    transpose_v<<<dim3(32, 64), 256, 0, stream>>>(qkvb, vtb);
    // 2) flash attention -> oat [8192,1024]  (4-wave blocks, shared staging)
    attn_kernel<<<512, 256, 0, stream>>>(qkvb, vtb, oat);
    // 3) proj -> pout (vt dead). grid 32x4.
    gemm256<<<dim3(32 * 4), 512, 0, stream>>>(oat, wprojb, proj_b, nullptr,
                                              pout, 1024, 1024, 0, 4);
    // 4) x1b = LN(x + pout)  (qkvb dead)
    ln_f32_bf16<<<8192, 256, 0, stream>>>(x, pout, ln1_g, ln1_b, x1b);
    // 5) h1 = PReLU(x1b @ w1^T + b1)  [8192,4096]. grid 32x16.
    gemm256<<<dim3(32 * 16), 512, 0, stream>>>(x1b, w1b, b1, prelu,
                                               h1, 4096, 1024, 0, 16);
    // 6) h2 = h1 @ w2^T + b2  [8192,1024]. grid 32x4, K=4096.
    gemm256<<<dim3(32 * 4), 512, 0, stream>>>(h1, w2b, b2, nullptr,
                                              h2, 1024, 4096, 0, 4);
    // 7) out = LN(x1b + h2)  (fp32 out)
    ln_bf16_f32<<<8192, 256, 0, stream>>>(x1b, h2, ln2_g, ln2_b, out);
}

// Round 3
// 485.751 us; speedup vs baseline: 1.1691x; 1.1691x over previous
//
#include <hip/hip_runtime.h>

// Inputs and output are FP32 (per the reference). Internal GEMM/attention
// compute is bf16 MFMA with fp32 accumulate; bf16 stored as unsigned short.

typedef __attribute__((ext_vector_type(8))) short short8;    // 8 bf16 = 1 MFMA A/B frag
typedef __attribute__((ext_vector_type(4))) short short4v;   // 4 bf16 = 8B vector
typedef __attribute__((ext_vector_type(4))) float floatx4;   // MFMA C/D frag
typedef __attribute__((ext_vector_type(4))) int int4v;

__device__ __forceinline__ float bf2f(unsigned short u) {
    return __uint_as_float(((unsigned int)u) << 16);
}
__device__ __forceinline__ unsigned short f2bf(float f) {
    unsigned int u = __float_as_uint(f);
    u += 0x7FFFu + ((u >> 16) & 1u);   // RNE
    return (unsigned short)(u >> 16);
}
__device__ __forceinline__ int pack2bf(float a, float b) {
    return (int)f2bf(a) | ((int)f2bf(b) << 16);
}
// Single-instruction packed f32->bf16 pair (RNE, matches f2bf).
__device__ __forceinline__ unsigned int cvt_pk_bf16(float lo, float hi) {
    unsigned int r;
    asm("v_cvt_pk_bf16_f32 %0, %1, %2" : "=v"(r) : "v"(lo), "v"(hi));
    return r;
}

// Q pre-scale folds softmax's 1/sqrt(64) AND log2(e) so the attention kernel
// can use the raw v_exp_f32 (2^x) instead of mul+exp: 0.125 * 1.4426950408889634
#define Q_PRESCALE 0.18033688011112043f

#if __has_builtin(__builtin_amdgcn_exp2f)
__device__ __forceinline__ float fast_exp2(float x) { return __builtin_amdgcn_exp2f(x); }
#else
__device__ __forceinline__ float fast_exp2(float x) { return __expf(x * 0.6931471805599453f); }
#endif

#if __has_builtin(__builtin_amdgcn_permlane32_swap) && __has_builtin(__builtin_amdgcn_permlane16_swap)
#define HAVE_PERMLANE 1
#else
#define HAVE_PERMLANE 0
#endif

// Async global->LDS, 16 B per lane. LDS dest = wave-uniform base + lane*16.
__device__ __forceinline__ void async16(const unsigned short* g, unsigned short* l) {
    __builtin_amdgcn_global_load_lds(
        (const __attribute__((address_space(1))) unsigned int*)g,
        (__attribute__((address_space(3))) unsigned int*)l, 16, 0, 0);
}

// ---------------------------------------------------------------------------
// FP32 -> BF16 elementwise convert. grid = n/1024, block 256.
// ---------------------------------------------------------------------------
__global__ __launch_bounds__(256)
void cvt_f2b(const float* __restrict__ in, unsigned short* __restrict__ out) {
    const int i = (blockIdx.x * 256 + threadIdx.x) * 4;
    float4 v = *(const float4*)&in[i];
    short4v o;
    o[0] = (short)f2bf(v.x); o[1] = (short)f2bf(v.y);
    o[2] = (short)f2bf(v.z); o[3] = (short)f2bf(v.w);
    *(short4v*)&out[i] = o;
}

// ---------------------------------------------------------------------------
// 256x256-tile 8-phase GEMM (T2+T3+T4+T5).
// C[M,N] = A[M,K] @ W[N,K]^T (+bias fp32) (+PReLU) (+Q_PRESCALE on cols<qcols)
// bf16 in/out, fp32 acc. BK=64, 8 waves (2M x 4N), 512 threads, 128 KiB LDS
// dbuf. Per K-tile: 4 phases, quadrants (0,0),(0,1),(1,1),(1,0); ds_reads
// 12/4/8/0; ONE counted vmcnt(6) per K-tile boundary (3 half-tiles stay in
// flight across barriers). FULL 3-bit XOR swizzle: LDS[row][chunk] holds
// global chunk (chunk ^ (row&7)); applied as inverse-swizzled GLOBAL source
// (global_load_lds dest must stay linear) + swizzled ds_read chunk. Each
// 16-B slot then serves exactly 2 lanes (rows r, r+8) -> conflict-free.
// WAR ledger (stage vs last read of region, 2 tiles apart):
//   A0 staged p1(t), read p0(t)   | B0 staged p2(t), read p0(t)
//   B1 staged p3(t), read p1(t)   | A1 staged p0(t+1), read p2(t)
// each read drains (lgkmcnt(0) + barrier) before its re-stage is issued.
// ---------------------------------------------------------------------------
__global__ __launch_bounds__(512, 2)
void gemm256(const unsigned short* __restrict__ A,
             const unsigned short* __restrict__ W,
             const float* __restrict__ bias,   // nullable, len N, fp32
             const float* __restrict__ prelu,  // nullable, scalar, fp32
             unsigned short* __restrict__ C,
             int N, int K, int qcols, int NNT) {
    __shared__ alignas(16) unsigned short lA[2][256 * 64];
    __shared__ alignas(16) unsigned short lB[2][256 * 64];

    // Bijective XCD swizzle (m204), then wgid = mt*NNT + nt.
    const int nwg = gridDim.x;
    const int orig = blockIdx.x;
    const int q8 = nwg >> 3, r8 = nwg & 7, xx = orig & 7, rest = orig >> 3;
    const int wgid = (xx < r8 ? xx * (q8 + 1) : r8 * (q8 + 1) + (xx - r8) * q8) + rest;
    const int mt = wgid / NNT, nt = wgid % NNT;
    const int m0 = mt * 256, n0 = nt * 256;

    const int tid  = threadIdx.x;
    const int lane = tid & 63;
    const int wave = tid >> 6;            // 0..7
    const int lr = lane & 15, lq = lane >> 4;
    const int wrow = (wave >> 2) * 64;    // wave row chunk within each M-half
    const int wcol = (wave & 3) * 32;     // wave col chunk within each N-half
    const int srow = lane >> 3;           // staging row within 8-row chunk (0..7)
    const int scol = ((lane & 7) ^ srow) << 3;   // inverse-swizzled source col
    const int kx = lr & 7;                       // read-side swizzle key

    const int NT = K >> 6;

    floatx4 acc[2][2][4][2] = {};   // [mh][nh][i][j]

    auto stA = [&](int d, int tt, int h) {
        #pragma unroll
        for (int it = 0; it < 2; ++it) {
            const int rb = h * 128 + (wave * 2 + it) * 8;
            async16(&A[(size_t)(m0 + rb + srow) * K + tt * 64 + scol], &lA[d][rb * 64]);
        }
    };
    auto stB = [&](int d, int tt, int h) {
        #pragma unroll
        for (int it = 0; it < 2; ++it) {
            const int rb = h * 128 + (wave * 2 + it) * 8;
            async16(&W[(size_t)(n0 + rb + srow) * K + tt * 64 + scol], &lB[d][rb * 64]);
        }
    };

    // Prologue: tile0 all 4 halves + tile1's first 3 = 14 loads; wait tile0.
    stA(0, 0, 0); stB(0, 0, 0); stB(0, 0, 1); stA(0, 0, 1);
    stA(1, 1, 0); stB(1, 1, 0); stB(1, 1, 1);
    asm volatile("s_waitcnt vmcnt(6)" ::: "memory");
    __builtin_amdgcn_s_barrier();
    asm volatile("" ::: "memory");

    short8 af[4][2], b0[2][2], b1[2][2];

    for (int t = 0; t < NT; ++t) {
        const int d = t & 1, e = d ^ 1;

        // ---- phase 0: read A0 + B0; stage A1(t+1); MFMA quad (0,0)
        #pragma unroll
        for (int i = 0; i < 4; ++i)
            #pragma unroll
            for (int s = 0; s < 2; ++s)
                af[i][s] = *(const short8*)&lA[d][(wrow + i * 16 + lr) * 64 +
                                                 (((s * 4 + lq) ^ kx) << 3)];
        #pragma unroll
        for (int j = 0; j < 2; ++j)
            #pragma unroll
            for (int s = 0; s < 2; ++s)
                b0[j][s] = *(const short8*)&lB[d][(wcol + j * 16 + lr) * 64 +
                                                 (((s * 4 + lq) ^ kx) << 3)];
        if (t + 1 < NT) stA(e, t + 1, 1);
        __builtin_amdgcn_s_barrier();
        asm volatile("s_waitcnt lgkmcnt(0)" ::: "memory");
        __builtin_amdgcn_s_setprio(1);
        #pragma unroll
        for (int s = 0; s < 2; ++s)
            #pragma unroll
            for (int i = 0; i < 4; ++i)
                #pragma unroll
                for (int j = 0; j < 2; ++j)
                    acc[0][0][i][j] = __builtin_amdgcn_mfma_f32_16x16x32_bf16(
                        af[i][s], b0[j][s], acc[0][0][i][j], 0, 0, 0);
        __builtin_amdgcn_s_setprio(0);
        __builtin_amdgcn_s_barrier();
        asm volatile("" ::: "memory");

        // ---- phase 1: read B1; stage A0(t+2); MFMA quad (0,1)
        #pragma unroll
        for (int j = 0; j < 2; ++j)
            #pragma unroll
            for (int s = 0; s < 2; ++s)
                b1[j][s] = *(const short8*)&lB[d][(128 + wcol + j * 16 + lr) * 64 +
                                                 (((s * 4 + lq) ^ kx) << 3)];
        if (t + 2 < NT) stA(d, t + 2, 0);
        __builtin_amdgcn_s_barrier();
        asm volatile("s_waitcnt lgkmcnt(0)" ::: "memory");
        __builtin_amdgcn_s_setprio(1);
        #pragma unroll
        for (int s = 0; s < 2; ++s)
            #pragma unroll
            for (int i = 0; i < 4; ++i)
                #pragma unroll
                for (int j = 0; j < 2; ++j)
                    acc[0][1][i][j] = __builtin_amdgcn_mfma_f32_16x16x32_bf16(
                        af[i][s], b1[j][s], acc[0][1][i][j], 0, 0, 0);
        __builtin_amdgcn_s_setprio(0);
        __builtin_amdgcn_s_barrier();
        asm volatile("" ::: "memory");

        // ---- phase 2: read A1; stage B0(t+2); MFMA quad (1,1)
        #pragma unroll
        for (int i = 0; i < 4; ++i)
            #pragma unroll
            for (int s = 0; s < 2; ++s)
                af[i][s] = *(const short8*)&lA[d][(128 + wrow + i * 16 + lr) * 64 +
                                                 (((s * 4 + lq) ^ kx) << 3)];
        if (t + 2 < NT) stB(d, t + 2, 0);
        __builtin_amdgcn_s_barrier();
        asm volatile("s_waitcnt lgkmcnt(0)" ::: "memory");
        __builtin_amdgcn_s_setprio(1);
        #pragma unroll
        for (int s = 0; s < 2; ++s)
            #pragma unroll
            for (int i = 0; i < 4; ++i)
                #pragma unroll
                for (int j = 0; j < 2; ++j)
                    acc[1][1][i][j] = __builtin_amdgcn_mfma_f32_16x16x32_bf16(
                        af[i][s], b1[j][s], acc[1][1][i][j], 0, 0, 0);
        __builtin_amdgcn_s_setprio(0);
        __builtin_amdgcn_s_barrier();
        asm volatile("" ::: "memory");

        // ---- phase 3: no reads; stage B1(t+2); MFMA quad (1,0); boundary
        if (t + 2 < NT) stB(d, t + 2, 1);
        __builtin_amdgcn_s_barrier();
        asm volatile("" ::: "memory");
        __builtin_amdgcn_s_setprio(1);
        #pragma unroll
        for (int s = 0; s < 2; ++s)
            #pragma unroll
            for (int i = 0; i < 4; ++i)
                #pragma unroll
                for (int j = 0; j < 2; ++j)
                    acc[1][0][i][j] = __builtin_amdgcn_mfma_f32_16x16x32_bf16(
                        af[i][s], b0[j][s], acc[1][0][i][j], 0, 0, 0);
        __builtin_amdgcn_s_setprio(0);
        // Boundary: all of tile t+1 done; keep t+2's 3 halves in flight.
        if (t + 2 < NT) {
            asm volatile("s_waitcnt vmcnt(6)" ::: "memory");
        } else {
            asm volatile("s_waitcnt vmcnt(0)" ::: "memory");
        }
        __builtin_amdgcn_s_barrier();
        asm volatile("" ::: "memory");
    }

    // Epilogue: bias / PReLU / Q prescale, bf16 store.
    const bool hasb = (bias != nullptr);
    const bool hasp = (prelu != nullptr);
    const float slope = hasp ? prelu[0] : 0.f;
    #pragma unroll
    for (int mh = 0; mh < 2; ++mh)
        #pragma unroll
        for (int nh = 0; nh < 2; ++nh)
            #pragma unroll
            for (int j = 0; j < 2; ++j) {
                const int gc = n0 + nh * 128 + wcol + j * 16 + lr;
                const float bv = hasb ? bias[gc] : 0.f;
                const float cs = (gc < qcols) ? Q_PRESCALE : 1.f;
                #pragma unroll
                for (int i = 0; i < 4; ++i) {
                    const int gr = m0 + mh * 128 + wrow + i * 16 + lq * 4;
                    #pragma unroll
                    for (int r = 0; r < 4; ++r) {
                        float v = acc[mh][nh][i][j][r] + bv;
                        if (hasp && v < 0.f) v *= slope;
                        C[(size_t)(gr + r) * N + gc] = f2bf(v * cs);
                    }
                }
            }
}

// ---------------------------------------------------------------------------
// 128x256-tile 2-phase GEMM for the N=1024/3072 shapes (exact CU fill:
// grid = (M/128)*(N/256)). Same 8-wave 2Mx4N layout, wave tile 64x64 over
// 2 N-halves. 96 KiB LDS dbuf. Regions per tile: A (128 rows), B0, B1.
// Phases: p0 = {read A(8)+B0(4); stage B1(t+1); MFMA nh=0};
//         p1 = {read B1(4); stage A(t+2)+B0(t+2); MFMA nh=1; vmcnt(4)}.
// Ledger: B1(t+1) staged p0(t) (region last read p1(t-1), drained);
// A/B0(t+2) staged p1(t) (read p0(t), drained via lgkm+barrier); boundary
// vmcnt(4) keeps only {A(t+2),B0(t+2)} in flight -> every region is
// drained one full tile before its read. Same full 3-bit XOR swizzle.
// ---------------------------------------------------------------------------
__global__ __launch_bounds__(512, 2)
void gemm128(const unsigned short* __restrict__ A,
             const unsigned short* __restrict__ W,
             const float* __restrict__ bias,
             const float* __restrict__ prelu,
             unsigned short* __restrict__ C,
             int N, int K, int qcols, int NNT) {
    __shared__ alignas(16) unsigned short lA[2][128 * 64];
    __shared__ alignas(16) unsigned short lB[2][256 * 64];

    const int nwg = gridDim.x;
    const int orig = blockIdx.x;
    const int q8 = nwg >> 3, r8 = nwg & 7, xx = orig & 7, rest = orig >> 3;
    const int wgid = (xx < r8 ? xx * (q8 + 1) : r8 * (q8 + 1) + (xx - r8) * q8) + rest;
    const int mt = wgid / NNT, nt = wgid % NNT;
    const int m0 = mt * 128, n0 = nt * 256;

    const int tid  = threadIdx.x;
    const int lane = tid & 63;
    const int wave = tid >> 6;            // 0..7
    const int lr = lane & 15, lq = lane >> 4;
    const int wrow = (wave >> 2) * 64;    // 2-way M split
    const int wcol = (wave & 3) * 32;     // 4-way N split within each half
    const int srow = lane >> 3;
    const int scol = ((lane & 7) ^ srow) << 3;
    const int kx = lr & 7;

    const int NT = K >> 6;

    floatx4 acc[2][4][2] = {};   // [nh][i][j]

    auto stA = [&](int d, int tt) {
        #pragma unroll
        for (int it = 0; it < 2; ++it) {
            const int rb = (wave * 2 + it) * 8;
            async16(&A[(size_t)(m0 + rb + srow) * K + tt * 64 + scol], &lA[d][rb * 64]);
        }
    };
    auto stB = [&](int d, int tt, int h) {
        #pragma unroll
        for (int it = 0; it < 2; ++it) {
            const int rb = (wave * 2 + it) * 8;
            async16(&W[(size_t)(n0 + h * 128 + rb + srow) * K + tt * 64 + scol],
                    &lB[d][(h * 128 + rb) * 64]);
        }
    };

    // Prologue: tile0 {A,B0,B1} + tile1 {A,B0} = 10 loads; wait tile0's 6.
    stA(0, 0); stB(0, 0, 0); stB(0, 0, 1);
    stA(1, 1); stB(1, 1, 0);
    asm volatile("s_waitcnt vmcnt(4)" ::: "memory");
    __builtin_amdgcn_s_barrier();
    asm volatile("" ::: "memory");

    short8 af[4][2], b0[2][2], b1[2][2];

    for (int t = 0; t < NT; ++t) {
        const int d = t & 1, e = d ^ 1;

        // ---- phase 0: read A + B0; stage B1(t+1); MFMA nh=0
        #pragma unroll
        for (int i = 0; i < 4; ++i)
            #pragma unroll
            for (int s = 0; s < 2; ++s)
                af[i][s] = *(const short8*)&lA[d][(wrow + i * 16 + lr) * 64 +
                                                 (((s * 4 + lq) ^ kx) << 3)];
        #pragma unroll
        for (int j = 0; j < 2; ++j)
            #pragma unroll
            for (int s = 0; s < 2; ++s)
                b0[j][s] = *(const short8*)&lB[d][(wcol + j * 16 + lr) * 64 +
                                                 (((s * 4 + lq) ^ kx) << 3)];
        if (t + 1 < NT) stB(e, t + 1, 1);
        __builtin_amdgcn_s_barrier();
        asm volatile("s_waitcnt lgkmcnt(0)" ::: "memory");
        __builtin_amdgcn_s_setprio(1);
        #pragma unroll
        for (int s = 0; s < 2; ++s)
            #pragma unroll
            for (int i = 0; i < 4; ++i)
                #pragma unroll
                for (int j = 0; j < 2; ++j)
                    acc[0][i][j] = __builtin_amdgcn_mfma_f32_16x16x32_bf16(
                        af[i][s], b0[j][s], acc[0][i][j], 0, 0, 0);
        __builtin_amdgcn_s_setprio(0);
        __builtin_amdgcn_s_barrier();
        asm volatile("" ::: "memory");

        // ---- phase 1: read B1; stage A(t+2)+B0(t+2); MFMA nh=1; boundary
        #pragma unroll
        for (int j = 0; j < 2; ++j)
            #pragma unroll
            for (int s = 0; s < 2; ++s)
                b1[j][s] = *(const short8*)&lB[d][(128 + wcol + j * 16 + lr) * 64 +
                                                 (((s * 4 + lq) ^ kx) << 3)];
        if (t + 2 < NT) { stA(d, t + 2); stB(d, t + 2, 0); }
        __builtin_amdgcn_s_barrier();
        asm volatile("s_waitcnt lgkmcnt(0)" ::: "memory");
        __builtin_amdgcn_s_setprio(1);
        #pragma unroll
        for (int s = 0; s < 2; ++s)
            #pragma unroll
            for (int i = 0; i < 4; ++i)
                #pragma unroll
                for (int j = 0; j < 2; ++j)
                    acc[1][i][j] = __builtin_amdgcn_mfma_f32_16x16x32_bf16(
                        af[i][s], b1[j][s], acc[1][i][j], 0, 0, 0);
        __builtin_amdgcn_s_setprio(0);
        if (t + 2 < NT) {
            asm volatile("s_waitcnt vmcnt(4)" ::: "memory");
        } else {
            asm volatile("s_waitcnt vmcnt(0)" ::: "memory");
        }
        __builtin_amdgcn_s_barrier();
        asm volatile("" ::: "memory");
    }

    // Epilogue.
    const bool hasb = (bias != nullptr);
    const bool hasp = (prelu != nullptr);
    const float slope = hasp ? prelu[0] : 0.f;
    #pragma unroll
    for (int nh = 0; nh < 2; ++nh)
        #pragma unroll
        for (int j = 0; j < 2; ++j) {
            const int gc = n0 + nh * 128 + wcol + j * 16 + lr;
            const float bv = hasb ? bias[gc] : 0.f;
            const float cs = (gc < qcols) ? Q_PRESCALE : 1.f;
            #pragma unroll
            for (int i = 0; i < 4; ++i) {
                const int gr = m0 + wrow + i * 16 + lq * 4;
                #pragma unroll
                for (int r = 0; r < 4; ++r) {
                    float v = acc[nh][i][j][r] + bv;
                    if (hasp && v < 0.f) v *= slope;
                    C[(size_t)(gr + r) * N + gc] = f2bf(v * cs);
                }
            }
        }
}

// ---------------------------------------------------------------------------
// V transpose: vt[(bh*64 + d)*2048 + key] = qkv[(b*2048+key)*3072 + 2048 + h*64 + d]
// ---------------------------------------------------------------------------
__global__ __launch_bounds__(256)
void transpose_v(const unsigned short* __restrict__ qkv,
                 unsigned short* __restrict__ vt) {
    const int kt = blockIdx.x;   // key tile 0..31
    const int bh = blockIdx.y;   // 0..63
    const int b = bh >> 4, h = bh & 15;
    __shared__ unsigned short tile[64 * 65];
    for (int t = threadIdx.x; t < 512; t += 256) {
        const int key = t >> 3, c8 = (t & 7) << 3;
        short8 v8 = *(const short8*)&qkv[((size_t)(b * 2048 + kt * 64 + key)) * 3072 +
                                         2048 + h * 64 + c8];
        #pragma unroll
        for (int e = 0; e < 8; ++e)
            tile[key * 65 + c8 + e] = (unsigned short)v8[e];
    }
    __syncthreads();
    for (int t = threadIdx.x; t < 512; t += 256) {
        const int d = t >> 3, k8 = (t & 7) << 3;
        short8 o;
        #pragma unroll
        for (int e = 0; e < 8; ++e)
            o[e] = (short)tile[(k8 + e) * 65 + d];
        *(short8*)&vt[((size_t)bh * 64 + d) * 2048 + kt * 64 + k8] = o;
    }
}

// ---------------------------------------------------------------------------
// Flash attention, S^T formulation, NO-MAX softmax (exp2; log2e folded into
// the Q pre-scale). FOUR WAVES PER BLOCK sharing the staged K/V chunk;
// double-buffered, raw s_barrier + counted `s_waitcnt vmcnt(4)`.
// K/V LDS tiles XOR-swizzled; P redistribution via permlane32/16_swap.
// Grid 512: id = qg*64 + bh -> id%8 = bh%8 (XCD locality for K/V).
// ---------------------------------------------------------------------------
__global__ __launch_bounds__(256, 2)
void attn_kernel(const unsigned short* __restrict__ qkv,
                 const unsigned short* __restrict__ vt,
                 unsigned short* __restrict__ o_attn) {
    const int id = blockIdx.x;
    const int qg = id >> 6;     // 0..7
    const int bh = id & 63;     // 0..63
    const int b = bh >> 4, h = bh & 15;
    const int tid  = threadIdx.x;
    const int lane = tid & 63;
    const int wave = tid >> 6;  // 0..3
    const int lr = lane & 15;
    const int lq = lane >> 4;
    const int q0 = (qg * 4 + wave) * 64;
    const size_t row0 = (size_t)(b * 2048) * 3072;

    __shared__ alignas(16) unsigned short lK[2][64 * 64];   // [key][d] (swizzled)
    __shared__ alignas(16) unsigned short lV[2][64 * 64];   // [d][key] (swizzled)

    // Q fragments (B-operand): [n = q = j*16+lr][k = s*32 + lq*8 + jj]
    short8 qf[4][2];
    #pragma unroll
    for (int j = 0; j < 4; ++j)
        #pragma unroll
        for (int s = 0; s < 2; ++s)
            qf[j][s] = *(const short8*)&qkv[row0 + (size_t)(q0 + j * 16 + lr) * 3072 +
                                            h * 64 + s * 32 + lq * 8];

    floatx4 oacc[4][4] = {};   // [dtile i][qtile j]: d=i*16+lq*4+r, q=j*16+lr
    float l_i[4] = {0.f, 0.f, 0.f, 0.f};

    const int srow = lane >> 3;                        // staging row-within-8
    const int scol = (((lane & 7) ^ srow)) << 3;       // swizzled source chunk
    const int kx = lr & 7;                             // read-side swizzle key

    // Stage one 64-key chunk into buffer bi: this wave's 2 K rows-of-8 + 2 V.
    auto stage = [&](int bi, int kc) {
        #pragma unroll
        for (int it2 = 0; it2 < 2; ++it2) {
            const int it = wave * 2 + it2;
            const int row = it * 8 + srow;            // row&7 == srow
            async16(&qkv[row0 + (size_t)(kc + row) * 3072 + 1024 + h * 64 + scol],
                    &lK[bi][it * 512 + lane * 8]);
            async16(&vt[((size_t)bh * 64 + row) * 2048 + kc + scol],
                    &lV[bi][it * 512 + lane * 8]);
        }
    };

    // Drain Q loads so vmcnt arithmetic below counts only staging loads.
    asm volatile("s_waitcnt vmcnt(0)" ::: "memory");
    stage(0, 0);

    #pragma unroll 1
    for (int c = 0; c < 32; ++c) {
        const int cur = c & 1;
        if (c + 1 < 32) {
            stage(cur ^ 1, (c + 1) * 64);            // issue next chunk's 4 loads
            asm volatile("s_waitcnt vmcnt(4)" ::: "memory");
        } else {
            asm volatile("s_waitcnt vmcnt(0)" ::: "memory");
        }
        __builtin_amdgcn_s_barrier();                // all waves staged `cur`
        asm volatile("" ::: "memory");

        // S^T = K·Q^T
        floatx4 sacc[4][4] = {};   // [keytile i][qtile j]: key=i*16+lq*4+r
        #pragma unroll
        for (int s = 0; s < 2; ++s) {
            short8 kf[4];
            #pragma unroll
            for (int i = 0; i < 4; ++i) {
                const int r = i * 16 + lr;
                kf[i] = *(const short8*)&lK[cur][r * 64 + (((s * 4 + lq) ^ kx) << 3)];
            }
            #pragma unroll
            for (int i = 0; i < 4; ++i)
                #pragma unroll
                for (int j = 0; j < 4; ++j)
                    sacc[i][j] = __builtin_amdgcn_mfma_f32_16x16x32_bf16(
                        kf[i], qf[j][s], sacc[i][j], 0, 0, 0);
        }

        // P = 2^S (log2e pre-folded), packed bf16 pairs via v_cvt_pk_bf16_f32.
        unsigned int pkd[4][4][2];
        #pragma unroll
        for (int i = 0; i < 4; ++i)
            #pragma unroll
            for (int j = 0; j < 4; ++j) {
                const float e0 = fast_exp2(sacc[i][j][0]);
                const float e1 = fast_exp2(sacc[i][j][1]);
                const float e2 = fast_exp2(sacc[i][j][2]);
                const float e3 = fast_exp2(sacc[i][j][3]);
                l_i[j] += (e0 + e1) + (e2 + e3);
                pkd[i][j][0] = cvt_pk_bf16(e0, e1);
                pkd[i][j][1] = cvt_pk_bf16(e2, e3);
            }

        // O^T += V^T·P^T.
        #pragma unroll
        for (int s = 0; s < 2; ++s) {
            short8 vf[4];
            #pragma unroll
            for (int i = 0; i < 4; ++i) {
                const int r = i * 16 + lr;
                vf[i] = *(const short8*)&lV[cur][r * 64 + (((s * 4 + lq) ^ kx) << 3)];
            }
            short8 bq[4];
            #pragma unroll
            for (int j = 0; j < 4; ++j) {
                int4v iv;
#if HAVE_PERMLANE
                auto p0 = __builtin_amdgcn_permlane32_swap(
                    pkd[2 * s][j][0], pkd[2 * s + 1][j][0], false, false);
                auto w0 = __builtin_amdgcn_permlane16_swap(p0[0], p0[1], false, false);
                auto p1 = __builtin_amdgcn_permlane32_swap(
                    pkd[2 * s][j][1], pkd[2 * s + 1][j][1], false, false);
                auto w1 = __builtin_amdgcn_permlane16_swap(p1[0], p1[1], false, false);
                iv[0] = (int)w0[0]; iv[1] = (int)w1[0];
                iv[2] = (int)w0[1]; iv[3] = (int)w1[1];
#else
                const int src0 = lr + ((lq & 1) * 2) * 16;
                const int src1 = src0 + 16;
                const bool hi = (lq >> 1) != 0;
                int a0 = __shfl((int)pkd[2 * s][j][0], src0, 64);
                int c0 = __shfl((int)pkd[2 * s + 1][j][0], src0, 64);
                int a1 = __shfl((int)pkd[2 * s][j][1], src0, 64);
                int c1 = __shfl((int)pkd[2 * s + 1][j][1], src0, 64);
                int a2 = __shfl((int)pkd[2 * s][j][0], src1, 64);
                int c2 = __shfl((int)pkd[2 * s + 1][j][0], src1, 64);
                int a3 = __shfl((int)pkd[2 * s][j][1], src1, 64);
                int c3 = __shfl((int)pkd[2 * s + 1][j][1], src1, 64);
                iv[0] = hi ? c0 : a0;
                iv[1] = hi ? c1 : a1;
                iv[2] = hi ? c2 : a2;
                iv[3] = hi ? c3 : a3;
#endif
                bq[j] = __builtin_bit_cast(short8, iv);
            }
            #pragma unroll
            for (int j = 0; j < 4; ++j)
                #pragma unroll
                for (int i = 0; i < 4; ++i)
                    oacc[i][j] = __builtin_amdgcn_mfma_f32_16x16x32_bf16(
                        vf[i], bq[j], oacc[i][j], 0, 0, 0);
        }

        asm volatile("s_waitcnt lgkmcnt(0)" ::: "memory");
        __builtin_amdgcn_s_barrier();
        asm volatile("" ::: "memory");
    }

    // Epilogue: reduce l across the 4 lq groups, normalize, packed stores.
    #pragma unroll
    for (int j = 0; j < 4; ++j) {
        l_i[j] += __shfl_xor(l_i[j], 16, 64);
        l_i[j] += __shfl_xor(l_i[j], 32, 64);
        const float rl = 1.f / l_i[j];
        const int q = q0 + j * 16 + lr;
        #pragma unroll
        for (int i = 0; i < 4; ++i) {
            int2 pk;
            pk.x = pack2bf(oacc[i][j][0] * rl, oacc[i][j][1] * rl);
            pk.y = pack2bf(oacc[i][j][2] * rl, oacc[i][j][3] * rl);
            *(int2*)&o_attn[((size_t)(b * 2048 + q)) * 1024 + h * 64 + i * 16 + lq * 4] = pk;
        }
    }
}

// ---------------------------------------------------------------------------
// LN1: out_bf16 = LayerNorm(x_fp32 + res_bf16) * g + b   (g,b fp32)
// ---------------------------------------------------------------------------
__global__ __launch_bounds__(256)
void ln_f32_bf16(const float* __restrict__ x,
                 const unsigned short* __restrict__ res,
                 const float* __restrict__ g,
                 const float* __restrict__ bta,
                 unsigned short* __restrict__ out) {
    const int row = blockIdx.x;
    const int t = threadIdx.x;
    const size_t base = (size_t)row * 1024;

    float4 xv = *(const float4*)&x[base + t * 4];
    short4v rv = *(const short4v*)&res[base + t * 4];
    float v[4] = { xv.x + bf2f((unsigned short)rv[0]),
                   xv.y + bf2f((unsigned short)rv[1]),
                   xv.z + bf2f((unsigned short)rv[2]),
                   xv.w + bf2f((unsigned short)rv[3]) };
    float s = 0.f, s2 = 0.f;
    #pragma unroll
    for (int k = 0; k < 4; ++k) { s += v[k]; s2 += v[k] * v[k]; }
    #pragma unroll
    for (int off = 32; off > 0; off >>= 1) {
        s  += __shfl_xor(s, off, 64);
        s2 += __shfl_xor(s2, off, 64);
    }
    __shared__ float red[8];
    const int wave = t >> 6;
    if ((t & 63) == 0) { red[wave] = s; red[4 + wave] = s2; }
    __syncthreads();
    s  = red[0] + red[1] + red[2] + red[3];
    s2 = red[4] + red[5] + red[6] + red[7];
    const float mean = s * (1.f / 1024.f);
    const float var  = fmaxf(s2 * (1.f / 1024.f) - mean * mean, 0.f);
    const float inv  = rsqrtf(var + 1e-5f);

    short4v ov;
    #pragma unroll
    for (int k = 0; k < 4; ++k) {
        int c = t * 4 + k;
        ov[k] = (short)f2bf((v[k] - mean) * inv * g[c] + bta[c]);
    }
    *(short4v*)&out[base + t * 4] = ov;
}

// ---------------------------------------------------------------------------
// LN2: out_fp32 = LayerNorm(x_bf16 + res_bf16) * g + b
// ---------------------------------------------------------------------------
__global__ __launch_bounds__(256)
void ln_bf16_f32(const unsigned short* __restrict__ x,
                 const unsigned short* __restrict__ res,
                 const float* __restrict__ g,
                 const float* __restrict__ bta,
                 float* __restrict__ out) {
    const int row = blockIdx.x;
    const int t = threadIdx.x;
    const size_t base = (size_t)row * 1024;

    short4v xv = *(const short4v*)&x[base + t * 4];
    short4v rv = *(const short4v*)&res[base + t * 4];
    float v[4];
    float s = 0.f, s2 = 0.f;
    #pragma unroll
    for (int k = 0; k < 4; ++k) {
        v[k] = bf2f((unsigned short)xv[k]) + bf2f((unsigned short)rv[k]);
        s += v[k];
        s2 += v[k] * v[k];
    }
    #pragma unroll
    for (int off = 32; off > 0; off >>= 1) {
        s  += __shfl_xor(s, off, 64);
        s2 += __shfl_xor(s2, off, 64);
    }
    __shared__ float red[8];
    const int wave = t >> 6;
    if ((t & 63) == 0) { red[wave] = s; red[4 + wave] = s2; }
    __syncthreads();
    s  = red[0] + red[1] + red[2] + red[3];
    s2 = red[4] + red[5] + red[6] + red[7];
    const float mean = s * (1.f / 1024.f);
    const float var  = fmaxf(s2 * (1.f / 1024.f) - mean * mean, 0.f);
    const float inv  = rsqrtf(var + 1e-5f);

    float4 ov;
    ov.x = (v[0] - mean) * inv * g[t * 4 + 0] + bta[t * 4 + 0];
    ov.y = (v[1] - mean) * inv * g[t * 4 + 1] + bta[t * 4 + 1];
    ov.z = (v[2] - mean) * inv * g[t * 4 + 2] + bta[t * 4 + 2];
    ov.w = (v[3] - mean) * inv * g[t * 4 + 3] + bta[t * 4 + 3];
    *(float4*)&out[base + t * 4] = ov;
}

// ---------------------------------------------------------------------------
extern "C" void kernel_launch(void* const* d_in, const int* in_sizes, int n_in,
                              void* d_out, int out_size, void* d_ws, size_t ws_size,
                              hipStream_t stream) {
    const float* x      = (const float*)d_in[0];
    const float* qkv_w  = (const float*)d_in[1];
    const float* proj_w = (const float*)d_in[2];
    const float* proj_b = (const float*)d_in[3];
    const float* ln1_g  = (const float*)d_in[4];
    const float* ln1_b  = (const float*)d_in[5];
    const float* w1     = (const float*)d_in[6];
    const float* b1     = (const float*)d_in[7];
    const float* prelu  = (const float*)d_in[8];
    const float* w2     = (const float*)d_in[9];
    const float* b2     = (const float*)d_in[10];
    const float* ln2_g  = (const float*)d_in[11];
    const float* ln2_b  = (const float*)d_in[12];
    float* out = (float*)d_out;

    // Workspace (bf16 buffers), peak 120 MB (validated):
    //  [0,24)   weights (qkv 6 | proj 2 | w1 8 | w2 8)
    //  [24,40)  xb -> vt (after qkv GEMM) -> pout (after attn) -> h2
    //  [40,88)  qkvb -> x1b[40,56)       [88,104) oat       h1 = [56,120)
    char* ws = (char*)d_ws;
    const size_t MB = 1024 * 1024;
    unsigned short* wqkvb  = (unsigned short*)(ws);
    unsigned short* wprojb = (unsigned short*)(ws + 6 * MB);
    unsigned short* w1b    = (unsigned short*)(ws + 8 * MB);
    unsigned short* w2b    = (unsigned short*)(ws + 16 * MB);
    unsigned short* xb     = (unsigned short*)(ws + 24 * MB);
    unsigned short* vtb    = (unsigned short*)(ws + 24 * MB);  // alias xb (dead)
    unsigned short* qkvb   = (unsigned short*)(ws + 40 * MB);
    unsigned short* oat    = (unsigned short*)(ws + 88 * MB);
    unsigned short* pout   = (unsigned short*)(ws + 24 * MB);  // alias vt (dead)
    unsigned short* x1b    = (unsigned short*)(ws + 40 * MB);
    unsigned short* h1     = (unsigned short*)(ws + 56 * MB);
    unsigned short* h2     = (unsigned short*)(ws + 24 * MB);

    // 0) fp32 -> bf16 conversions
    cvt_f2b<<<8192, 256, 0, stream>>>(x,      xb);
    cvt_f2b<<<3072, 256, 0, stream>>>(qkv_w,  wqkvb);
    cvt_f2b<<<1024, 256, 0, stream>>>(proj_w, wprojb);
    cvt_f2b<<<4096, 256, 0, stream>>>(w1,     w1b);
    cvt_f2b<<<4096, 256, 0, stream>>>(w2,     w2b);

    // 1) qkv = x @ qkv_w^T  [8192,3072], Q cols pre-scaled 0.125*log2e.
    //    gemm128: grid 64*12 = 768 = 3.0 blocks/CU (exact fill).
    gemm128<<<dim3(64 * 12), 512, 0, stream>>>(xb, wqkvb, nullptr, nullptr,
                                               qkvb, 3072, 1024, 1024, 12);
    // 1b) V transpose -> vt[bh][d][key]  (xb dead)
    transpose_v<<<dim3(32, 64), 256, 0, stream>>>(qkvb, vtb);
    // 2) flash attention -> oat [8192,1024]  (4-wave blocks, shared staging)
    attn_kernel<<<512, 256, 0, stream>>>(qkvb, vtb, oat);
    // 3) proj -> pout (vt dead). gemm128: grid 64*4 = 256 = 1.0/CU.
    gemm128<<<dim3(64 * 4), 512, 0, stream>>>(oat, wprojb, proj_b, nullptr,
                                              pout, 1024, 1024, 0, 4);
    // 4) x1b = LN(x + pout)  (qkvb dead)
    ln_f32_bf16<<<8192, 256, 0, stream>>>(x, pout, ln1_g, ln1_b, x1b);
    // 5) h1 = PReLU(x1b @ w1^T + b1)  [8192,4096]. gemm256: grid 512 = 2.0/CU.
    gemm256<<<dim3(32 * 16), 512, 0, stream>>>(x1b, w1b, b1, prelu,
                                               h1, 4096, 1024, 0, 16);
    // 6) h2 = h1 @ w2^T + b2  [8192,1024]. gemm128: grid 256, K=4096.
    gemm128<<<dim3(64 * 4), 512, 0, stream>>>(h1, w2b, b2, nullptr,
                                              h2, 1024, 4096, 0, 4);
    // 7) out = LN(x1b + h2)  (fp32 out)
    ln_bf16_f32<<<8192, 256, 0, stream>>>(x1b, h2, ln2_g, ln2_b, out);
}